// Round 1
// baseline (237.446 us; speedup 1.0000x reference)
//
#include <hip/hip_runtime.h>

#define BB 32
#define LL 1024
#define HH 384
#define H4 (HH / 4)   // 96 float4 per row
#define TT 64         // t-positions per block (gather)
#define NT 256        // threads per block

// ---------------------------------------------------------------------------
// Kernel A: one block per batch. Scan durations once, scatter the inverse map
// srcidx[b][t] = source token index (or -1 past total), and write the mask.
// ---------------------------------------------------------------------------
__global__ __launch_bounds__(NT) void expand_kernel(
    const int* __restrict__ dur,     // (B, L) i32
    int* __restrict__ srcidx,        // (B, T) i32 workspace
    float* __restrict__ mask,        // (B, T) f32
    int T)
{
    __shared__ int psum[NT];

    const int tid = threadIdx.x;
    const int b   = blockIdx.x;

    // each thread loads 4 consecutive durations
    int4 d = ((const int4*)(dur + (size_t)b * LL))[tid];
    int p0 = d.x;
    int p1 = p0 + d.y;
    int p2 = p1 + d.z;
    int p3 = p2 + d.w;
    psum[tid] = p3;
    __syncthreads();
    // Hillis-Steele inclusive scan over 256 partials
    #pragma unroll
    for (int off = 1; off < NT; off <<= 1) {
        int v = (tid >= off) ? psum[tid - off] : 0;
        __syncthreads();
        psum[tid] += v;
        __syncthreads();
    }
    const int excl  = (tid > 0) ? psum[tid - 1] : 0;
    const int total = psum[NT - 1];

    // scatter spans: token l covers positions [cum[l-1], cum[l])
    int* __restrict__ sb = srcidx + (size_t)b * T;
    const int e0 = excl + p0;
    const int e1 = excl + p1;
    const int e2 = excl + p2;
    const int e3 = excl + p3;
    const int l0 = 4 * tid;
    for (int k = excl; k < e0; ++k) sb[k] = l0 + 0;
    for (int k = e0;   k < e1; ++k) sb[k] = l0 + 1;
    for (int k = e1;   k < e2; ++k) sb[k] = l0 + 2;
    for (int k = e2;   k < e3; ++k) sb[k] = l0 + 3;

    // tail: positions past total get -1
    for (int t = total + tid; t < T; t += NT) sb[t] = -1;

    // mask for the whole row, coalesced
    float* __restrict__ mb = mask + (size_t)b * T;
    for (int t = tid; t < T; t += NT) mb[t] = (t < total) ? 1.0f : 0.0f;
}

// ---------------------------------------------------------------------------
// Kernel B: pure streaming gather. No LDS, no barriers, no scan.
// Each block copies TT=64 rows x 96 float4, fully coalesced.
// ---------------------------------------------------------------------------
__global__ __launch_bounds__(NT) void gather_kernel(
    const float* __restrict__ ehs,   // (B, L, H) f32
    const int* __restrict__ srcidx,  // (B, T) i32
    float* __restrict__ out,         // (B, T, H) f32
    int T)
{
    const int b  = blockIdx.y;
    const int t0 = blockIdx.x * TT;

    const float4* __restrict__ src = (const float4*)(ehs + (size_t)b * LL * HH);
    float4* __restrict__ ob        = (float4*)out + ((size_t)b * T + t0) * (size_t)H4;
    const int* __restrict__ sb     = srcidx + (size_t)b * T + t0;
    const float4 zero4 = make_float4(0.f, 0.f, 0.f, 0.f);

    if (t0 + TT <= T) {
        // fast path: compile-time trip count, fully unrolled
        #pragma unroll
        for (int i = 0; i < (TT * H4) / NT; ++i) {
            const int w   = threadIdx.x + i * NT;
            const int tl  = w / H4;          // constant div -> magic mul
            const int v   = w - tl * H4;
            const int idx = sb[tl];          // L1-broadcast read
            float4 val = zero4;
            if (idx >= 0) val = src[(size_t)idx * H4 + v];
            ob[w] = val;
        }
    } else {
        const int wmax = (T - t0) * H4;
        for (int w = threadIdx.x; w < wmax; w += NT) {
            const int tl  = w / H4;
            const int v   = w - tl * H4;
            const int idx = sb[tl];
            float4 val = zero4;
            if (idx >= 0) val = src[(size_t)idx * H4 + v];
            ob[w] = val;
        }
    }
}

// ---------------------------------------------------------------------------
// Fallback: previous verified single-kernel version (used if ws too small).
// ---------------------------------------------------------------------------
__global__ __launch_bounds__(NT) void lenreg_kernel(
    const float* __restrict__ ehs,
    const int* __restrict__ dur,
    float* __restrict__ out,
    float* __restrict__ mask,
    int T)
{
    __shared__ int scum[LL];
    __shared__ int psum[NT];
    __shared__ int sidx[TT];

    const int tid = threadIdx.x;
    const int b   = blockIdx.y;
    const int t0  = blockIdx.x * TT;

    int4 d = ((const int4*)(dur + (size_t)b * LL))[tid];
    int p0 = d.x;
    int p1 = p0 + d.y;
    int p2 = p1 + d.z;
    int p3 = p2 + d.w;
    psum[tid] = p3;
    __syncthreads();
    #pragma unroll
    for (int off = 1; off < NT; off <<= 1) {
        int v = (tid >= off) ? psum[tid - off] : 0;
        __syncthreads();
        psum[tid] += v;
        __syncthreads();
    }
    const int excl = (tid > 0) ? psum[tid - 1] : 0;
    scum[4 * tid + 0] = excl + p0;
    scum[4 * tid + 1] = excl + p1;
    scum[4 * tid + 2] = excl + p2;
    scum[4 * tid + 3] = excl + p3;
    __syncthreads();

    const int total = scum[LL - 1];

    if (tid < TT) {
        const int t = t0 + tid;
        int lo = 0, hi = LL;
        while (lo < hi) {
            const int mid = (lo + hi) >> 1;
            if (scum[mid] <= t) lo = mid + 1; else hi = mid;
        }
        sidx[tid] = (lo < LL - 1) ? lo : (LL - 1);
        if (t < T) mask[(size_t)b * T + t] = (t < total) ? 1.0f : 0.0f;
    }
    __syncthreads();

    const float4* __restrict__ src_base = (const float4*)(ehs + (size_t)b * LL * HH);
    float4* __restrict__ out4 = (float4*)out;
    const float4 zero4 = make_float4(0.f, 0.f, 0.f, 0.f);

    for (int w = tid; w < TT * H4; w += NT) {
        const int tl = w / H4;
        const int v  = w - tl * H4;
        const int t  = t0 + tl;
        if (t >= T) break;
        float4 val = zero4;
        if (t < total) {
            val = src_base[(size_t)sidx[tl] * H4 + v];
        }
        out4[((size_t)b * T + t) * H4 + v] = val;
    }
}

extern "C" void kernel_launch(void* const* d_in, const int* in_sizes, int n_in,
                              void* d_out, int out_size, void* d_ws, size_t ws_size,
                              hipStream_t stream) {
    const float* ehs = (const float*)d_in[0];
    const int*   dur = (const int*)d_in[1];

    // out_size = B*T*H + B*T = B*T*(H+1)
    const int T = out_size / (BB * (HH + 1));

    float* out  = (float*)d_out;
    float* mask = (float*)d_out + (size_t)BB * T * HH;

    const size_t need = (size_t)BB * (size_t)T * sizeof(int);
    dim3 grid((T + TT - 1) / TT, BB);
    dim3 block(NT);

    if (d_ws != nullptr && ws_size >= need) {
        int* srcidx = (int*)d_ws;
        expand_kernel<<<dim3(BB), block, 0, stream>>>(dur, srcidx, mask, T);
        gather_kernel<<<grid, block, 0, stream>>>(ehs, srcidx, out, T);
    } else {
        lenreg_kernel<<<grid, block, 0, stream>>>(ehs, dur, out, mask, T);
    }
}

// Round 4
// 227.456 us; speedup vs baseline: 1.0439x; 1.0439x over previous
//
#include <hip/hip_runtime.h>

#define BB 32
#define LL 1024
#define HH 384
#define H4 (HH / 4)   // 96 float4 per row
#define TT 64         // t-positions per block
#define NT 256        // threads per block
#define NW (NT / 64)  // waves per block
#define WPT (TT * H4 / NT)  // float4 per thread in a full tile = 24

typedef float f4 __attribute__((ext_vector_type(4)));   // native vector: nt-store OK

__global__ __launch_bounds__(NT) void lenreg_kernel(
    const float* __restrict__ ehs,   // (B, L, H) f32
    const int* __restrict__ dur,     // (B, L) i32
    float* __restrict__ out,         // (B, T, H) f32
    float* __restrict__ mask,        // (B, T) f32
    int T)
{
    __shared__ int scum[LL];     // inclusive cumsum of durations for this batch
    __shared__ int wsum[NW];     // per-wave totals
    __shared__ int sidx[TT];     // source token index per t in this tile

    const int tid  = threadIdx.x;
    const int lane = tid & 63;
    const int wid  = tid >> 6;
    const int b    = blockIdx.y;
    const int t0   = blockIdx.x * TT;

    // ---- cumsum of durations[b,:]: wave-level shfl scan, only 3 barriers ----
    int4 d = ((const int4*)(dur + (size_t)b * LL))[tid];
    const int p0 = d.x;
    const int p1 = p0 + d.y;
    const int p2 = p1 + d.z;
    const int p3 = p2 + d.w;

    // inclusive scan of p3 across the 64-lane wave (no barriers)
    int v = p3;
    #pragma unroll
    for (int off = 1; off < 64; off <<= 1) {
        const int n = __shfl_up(v, off, 64);
        if (lane >= off) v += n;
    }
    if (lane == 63) wsum[wid] = v;
    __syncthreads();

    int woff = 0, total = 0;
    #pragma unroll
    for (int w = 0; w < NW; ++w) {
        const int s = wsum[w];
        woff  += (w < wid) ? s : 0;
        total += s;
    }

    const int excl = woff + v - p3;   // exclusive prefix for this thread's 4 tokens
    scum[4 * tid + 0] = excl + p0;
    scum[4 * tid + 1] = excl + p1;
    scum[4 * tid + 2] = excl + p2;
    scum[4 * tid + 3] = excl + p3;
    __syncthreads();

    // ---- branchless pow2 lower-bound: pos = #(cum <= t), then clamp ----
    if (tid < TT) {
        const int t = t0 + tid;
        int pos = 0;
        #pragma unroll
        for (int step = LL / 2; step > 0; step >>= 1) {
            if (scum[pos + step - 1] <= t) pos += step;   // max probe = 1023, exact
        }
        sidx[tid] = (pos < LL - 1) ? pos : (LL - 1);
        if (t < T) mask[(size_t)b * T + t] = (t < total) ? 1.0f : 0.0f;
    }
    __syncthreads();

    // ---- gather + store ----
    const f4* __restrict__ src = (const f4*)(ehs + (size_t)b * LL * HH);
    f4* __restrict__ ob = (f4*)out + ((size_t)b * T + t0) * (size_t)H4;

    const int tlim = (T < total) ? T : total;
    if (t0 + TT <= tlim) {
        // fast path: every t in the tile is live -> branchless, fully unrolled,
        // idx reads hoisted, non-temporal stores (write stream has no reuse)
        int idxr[WPT];
        #pragma unroll
        for (int i = 0; i < WPT; ++i) {
            idxr[i] = sidx[(tid + i * NT) / H4];
        }
        #pragma unroll
        for (int i = 0; i < WPT; ++i) {
            const int w  = tid + i * NT;
            const int tl = w / H4;           // compile-time magic-mul
            const int vv = w - tl * H4;
            const f4 val = src[(size_t)idxr[i] * H4 + vv];
            __builtin_nontemporal_store(val, &ob[w]);
        }
    } else {
        // tail path: predicated
        const int tend = (T < t0 + TT) ? T : (t0 + TT);
        const int wmax = (tend > t0) ? (tend - t0) * H4 : 0;
        const f4 zero4 = (f4){0.f, 0.f, 0.f, 0.f};
        for (int w = tid; w < wmax; w += NT) {
            const int tl = w / H4;
            const int vv = w - tl * H4;
            const int t  = t0 + tl;
            f4 val = zero4;
            if (t < total) val = src[(size_t)sidx[tl] * H4 + vv];
            __builtin_nontemporal_store(val, &ob[w]);
        }
    }
}

extern "C" void kernel_launch(void* const* d_in, const int* in_sizes, int n_in,
                              void* d_out, int out_size, void* d_ws, size_t ws_size,
                              hipStream_t stream) {
    const float* ehs = (const float*)d_in[0];
    const int*   dur = (const int*)d_in[1];

    // out_size = B*T*H + B*T = B*T*(H+1)
    const int T = out_size / (BB * (HH + 1));

    float* out  = (float*)d_out;
    float* mask = (float*)d_out + (size_t)BB * T * HH;

    dim3 grid((T + TT - 1) / TT, BB);
    dim3 block(NT);
    lenreg_kernel<<<grid, block, 0, stream>>>(ehs, dur, out, mask, T);
}